// Round 3
// baseline (492.235 us; speedup 1.0000x reference)
//
#include <hip/hip_runtime.h>
#include <hip/hip_bf16.h>
#include <stdint.h>

typedef __hip_bfloat16 bf16;
typedef __attribute__((ext_vector_type(4))) float f32x4;
typedef __attribute__((ext_vector_type(16))) float f32x16;
typedef __attribute__((ext_vector_type(8))) short bf16x8;

#define B_  2
#define S_  2048
#define HID_ 2048
#define NH_ 16
#define NKV_ 2
#define HD_ 128
#define QKV_N 2560           // (NH + 2*NKV) * HD
// SCALE * log2(e): scores in log2 domain so softmax exp is v_exp_f32
#define QSCALE_ (0.08838834764831845f * 1.4426950408889634f)

__device__ __forceinline__ void async_load16(const void* g, void* l) {
    __builtin_amdgcn_global_load_lds(
        (const __attribute__((address_space(1))) unsigned int*)(uintptr_t)g,
        (__attribute__((address_space(3))) unsigned int*)(uintptr_t)l,
        16, 0, 0);
}

__device__ __forceinline__ short f2bf(float f) {
    __hip_bfloat16 h = __float2bfloat16(f);
    return *reinterpret_cast<short*>(&h);
}

// ---------------------------------------------------------------------------
// prep1: fused X cast + Wqkv transpose-cast (phi-permuted) + Wo transpose-cast
__global__ void prep1(const float* __restrict__ X, bf16* __restrict__ Xb,
                      const float* __restrict__ Wqkv, bf16* __restrict__ Wqkvt,
                      const float* __restrict__ Wo, bf16* __restrict__ Wot)
{
    __shared__ float t[32][33];
    int bid = blockIdx.x;
    if (bid < 8192) {
        long idx = ((long)bid * 256 + threadIdx.x) * 4;
        float4 v = *(const float4*)(X + idx);
        bf16 o[4];
        o[0] = __float2bfloat16(v.x); o[1] = __float2bfloat16(v.y);
        o[2] = __float2bfloat16(v.z); o[3] = __float2bfloat16(v.w);
        *(ulong1*)(Xb + idx) = *(ulong1*)o;
        return;
    }
    const float* in; bf16* out; int R, C, bx, by; bool perm;
    if (bid < 13312) {
        int v = bid - 8192;          // (80, 64)
        bx = v % 80; by = v / 80;
        in = Wqkv; out = Wqkvt; R = HID_; C = QKV_N; perm = true;
    } else {
        int v = bid - 13312;         // (64, 64)
        bx = v & 63; by = v >> 6;
        in = Wo; out = Wot; R = HID_; C = HID_; perm = false;
    }
    int tx = threadIdx.x & 31, ty = threadIdx.x >> 5;   // 32x8
    int c = bx * 32 + tx;
#pragma unroll
    for (int j = 0; j < 4; j++) {
        int r = by * 32 + ty + j * 8;
        t[ty + j * 8][tx] = in[(long)r * C + c];
    }
    __syncthreads();
#pragma unroll
    for (int j = 0; j < 4; j++) {
        int cc = bx * 32 + ty + j * 8;
        int rr = by * 32 + tx;
        int ccp = cc;
        if (perm && cc < (NH_ + NKV_) * HD_)   // Q/K heads: swap bits 5,6
            ccp = (cc & ~0x60) | ((cc & 0x20) << 1) | ((cc & 0x40) >> 1);
        out[(long)ccp * R + rr] = __float2bfloat16(t[tx][ty + j * 8]);
    }
}

// ---------------------------------------------------------------------------
// v_transpose: Vtmp[b][s][j] (bias already applied) -> VtG[b][j][sigma(s)],
// sigma = swap bits 2<->3 of s (PV A-fragment key ordering).
__global__ void v_transpose(const bf16* __restrict__ Vtmp, bf16* __restrict__ VtG) {
    __shared__ bf16 t[32][33];
    int v = blockIdx.x;                       // (8, 64, 2) flattened
    int j0 = (v & 7) * 32;
    int s0 = ((v >> 3) & 63) * 32;
    int b = v >> 9;
    int tx = threadIdx.x & 31, ty = threadIdx.x >> 5;   // 32x8
#pragma unroll
    for (int jj = 0; jj < 4; jj++) {
        int s = s0 + ty + jj * 8;
        t[ty + jj * 8][tx] = Vtmp[((long)b * S_ + s) * 256 + j0 + tx];
    }
    __syncthreads();
    int txp = (tx & 0x13) | ((tx & 4) << 1) | ((tx & 8) >> 1);  // swap bits 2,3
#pragma unroll
    for (int jj = 0; jj < 4; jj++) {
        int j = j0 + ty + jj * 8;
        VtG[((long)b * (2 * HD_) + j) * S_ + s0 + txp] = t[tx][ty + jj * 8];
    }
}

// ---------------------------------------------------------------------------
// Prefetch-shifted phase GEMM core. BN=256, BK=64, 8 waves (2M x 4N),
// double-buffered LDS. Quadrant order (0,0),(1,0),(1,1),(0,1) with NO
// fragment re-reads (24 ds_read_b128 per wave per K-tile). Each phase
// PREFETCHES the next phase's fragments while MFMAing the current ones,
// so LDS-read latency hides under the matrix pipe (rounds 1-2 read
// synchronously per phase -> serialized, 541 TF).
//   P1: MFMA(A0,B0) | prefetch A1       | stage A0,B0(t+1) -> buf^1
//   P2: MFMA(A1,B0) | prefetch B1       | stage A1,B1(t+1) -> buf^1
//   P3: MFMA(A1,B1) | vmcnt(LA+2)+bar   (P1 stages complete, 2 phases old)
//   P4: MFMA(A0,B1) | prefetch A0,B0(t+1) from buf^1 | vmcnt(0)+bar
// A0/B0 fragments double-buffered via 2x-unrolled loop (compile-time roles).
// EPI: 0 = plain fp32 store (out proj), 1 = QKV bias+RoPE epilogue.
template<int BM, int EPI>
__global__ __launch_bounds__(512, 2) void gemm_core(
    const bf16* __restrict__ A, const bf16* __restrict__ Bt,
    const float* __restrict__ bias, const int* __restrict__ pos,
    bf16* __restrict__ Qr, bf16* __restrict__ Kr, bf16* __restrict__ Vtmp,
    float* __restrict__ Fout, const int Nn)
{
    constexpr int K    = HID_;
    constexpr int NT   = K / 64;        // 32 K-tiles (even)
    constexpr int AH   = BM / 2;        // rows per A half-region
    constexpr int SW   = BM / 4;        // per-wave rows per quadrant
    constexpr int MFH  = SW / 16;       // M-frags per quadrant (4 or 2)
    constexpr int ABYTES = BM * 128;    // A region bytes per buffer
    constexpr int BUFB   = (BM + 256) * 128;
    constexpr int LA     = (AH * 128) / 8192;   // stage loads per A-half (2 or 1)

    extern __shared__ char smem[];

    const int tid  = threadIdx.x;
    const int wave = tid >> 6, lane = tid & 63;
    const int quad = lane >> 4, l16 = lane & 15;
    const int wm = wave >> 2, wn = wave & 3;
    const long row0 = (long)blockIdx.y * BM;
    const long col0 = (long)blockIdx.x * 256;

    // ---- persistent per-lane stage source pointers (advance by imm) ----
    const char* sA0[LA]; int dA0[LA];
    const char* sB0[2];  int dB0[2];
#pragma unroll
    for (int s = 0; s < LA; ++s) {
        int ob = wave * 1024 + s * 8192;
        int o  = ob + lane * 16;
        int rl = o >> 7, sc = (o >> 4) & 7;
        int gc = (sc ^ (rl & 7)) * 8;
        int wmm = rl / SW, low = rl % SW;
        long ra = row0 + (long)wmm * (BM / 2) + low;   // h adds SW rows
        sA0[s] = (const char*)(A + ra * K + gc);
        dA0[s] = ob;
    }
#pragma unroll
    for (int s = 0; s < 2; ++s) {
        int ob = wave * 1024 + s * 8192;
        int o  = ob + lane * 16;
        int rl = o >> 7, sc = (o >> 4) & 7;
        int gc = (sc ^ (rl & 7)) * 8;
        int wnn = rl >> 5, low = rl & 31;
        long cb = col0 + wnn * 64 + low;               // h adds 32 rows
        sB0[s] = (const char*)(Bt + cb * K + gc);
        dB0[s] = ABYTES + ob;
    }

    auto stageA = [&](int t1, int h, int bufp) {
#pragma unroll
        for (int s = 0; s < LA; ++s)
            async_load16(sA0[s] + (size_t)h * ((size_t)SW * K * 2) + (size_t)t1 * 128,
                         smem + (size_t)bufp * BUFB + h * (AH * 128) + dA0[s]);
    };
    auto stageB = [&](int t1, int h, int bufp) {
#pragma unroll
        for (int s = 0; s < 2; ++s)
            async_load16(sB0[s] + (size_t)h * ((size_t)32 * K * 2) + (size_t)t1 * 128,
                         smem + (size_t)bufp * BUFB + h * 16384 + dB0[s]);
    };

    f32x4 acc[2 * MFH][4];
#pragma unroll
    for (int i = 0; i < 2 * MFH; i++)
#pragma unroll
        for (int j = 0; j < 4; j++) acc[i][j] = {0.f, 0.f, 0.f, 0.f};

    // fragment registers: A0/B0 double-buffered (role-swapped per tile parity)
    bf16x8 aq0a[MFH][2], aq0b[MFH][2], bq0a[2][2], bq0b[2][2];
    bf16x8 aq1[MFH][2], bq1[2][2];

    auto loadA = [&](bf16x8 (&d)[MFH][2], const bf16* base, int qm) {
#pragma unroll
        for (int mi = 0; mi < MFH; ++mi)
#pragma unroll
            for (int ks = 0; ks < 2; ++ks)
                d[mi][ks] = *(const bf16x8*)(base +
                    (qm * AH + wm * SW + mi * 16 + l16) * 64 +
                    (((ks * 4 + quad) ^ (l16 & 7)) * 8));
    };
    auto loadB = [&](bf16x8 (&d)[2][2], const bf16* base, int qn) {
#pragma unroll
        for (int ni = 0; ni < 2; ++ni)
#pragma unroll
            for (int ks = 0; ks < 2; ++ks)
                d[ni][ks] = *(const bf16x8*)(base +
                    (qn * 128 + wn * 32 + ni * 16 + l16) * 64 +
                    (((ks * 4 + quad) ^ (l16 & 7)) * 8));
    };
    auto mfmaQ = [&](bf16x8 (&a)[MFH][2], bf16x8 (&b)[2][2], int mg0, int j0) {
#pragma unroll
        for (int ks = 0; ks < 2; ++ks)
#pragma unroll
            for (int mi = 0; mi < MFH; ++mi)
#pragma unroll
                for (int ni = 0; ni < 2; ++ni)
                    acc[mg0 + mi][j0 + ni] =
                        __builtin_amdgcn_mfma_f32_16x16x32_bf16(
                            a[mi][ks], b[ni][ks], acc[mg0 + mi][j0 + ni],
                            0, 0, 0);
    };

    auto tile_body = [&](int t, int cur,
                         bf16x8 (&AQ0)[MFH][2], bf16x8 (&AQ0N)[MFH][2],
                         bf16x8 (&BQ0)[2][2],  bf16x8 (&BQ0N)[2][2]) {
        const bf16* Ab  = (const bf16*)(smem + cur * BUFB);
        const bf16* Bb  = (const bf16*)(smem + cur * BUFB + ABYTES);
        const bf16* Abn = (const bf16*)(smem + (cur ^ 1) * BUFB);
        const bf16* Bbn = (const bf16*)(smem + (cur ^ 1) * BUFB + ABYTES);
        const bool st = (t + 1 < NT);

        // ---- P1: MFMA(0,0); prefetch A1; stage A0,B0(t+1) ----
        loadA(aq1, Ab, 1);
        if (st) { stageA(t + 1, 0, cur ^ 1); stageB(t + 1, 0, cur ^ 1); }
        __builtin_amdgcn_s_setprio(1);
        mfmaQ(AQ0, BQ0, 0, 0);
        __builtin_amdgcn_s_setprio(0);
        __builtin_amdgcn_s_barrier();

        // ---- P2: MFMA(1,0); prefetch B1; stage A1,B1(t+1) ----
        loadB(bq1, Bb, 1);
        if (st) { stageA(t + 1, 1, cur ^ 1); stageB(t + 1, 1, cur ^ 1); }
        __builtin_amdgcn_s_setprio(1);
        mfmaQ(aq1, BQ0, MFH, 0);
        __builtin_amdgcn_s_setprio(0);
        __builtin_amdgcn_s_barrier();

        // ---- P3: MFMA(1,1); drain P1's stages (2 phases old) ----
        __builtin_amdgcn_s_setprio(1);
        mfmaQ(aq1, bq1, MFH, 2);
        __builtin_amdgcn_s_setprio(0);
        if (st) asm volatile("s_waitcnt vmcnt(%0)" :: "i"(LA + 2) : "memory");
        else    asm volatile("s_waitcnt vmcnt(0)" ::: "memory");
        __builtin_amdgcn_s_barrier();

        // ---- P4: prefetch next A0,B0 from buf^1; MFMA(0,1); drain rest ----
        if (st) { loadA(AQ0N, Abn, 0); loadB(BQ0N, Bbn, 0); }
        __builtin_amdgcn_s_setprio(1);
        mfmaQ(AQ0, bq1, 0, 2);
        __builtin_amdgcn_s_setprio(0);
        asm volatile("s_waitcnt vmcnt(0)" ::: "memory");
        __builtin_amdgcn_s_barrier();
    };

    // ---- prologue: stage tile0 fully, drain, prefetch A0/B0 frags ----
    stageA(0, 0, 0); stageB(0, 0, 0);
    stageA(0, 1, 0); stageB(0, 1, 0);
    asm volatile("s_waitcnt vmcnt(0)" ::: "memory");
    __builtin_amdgcn_s_barrier();
    loadA(aq0a, (const bf16*)smem, 0);
    loadB(bq0a, (const bf16*)(smem + ABYTES), 0);

#pragma unroll 1
    for (int t2 = 0; t2 < NT; t2 += 2) {
        tile_body(t2,     0, aq0a, aq0b, bq0a, bq0b);
        tile_body(t2 + 1, 1, aq0b, aq0a, bq0b, bq0a);
    }

    // ---- epilogue ----
    if constexpr (EPI == 0) {
#pragma unroll
        for (int mg = 0; mg < 2 * MFH; ++mg) {
            long r = row0 + wm * (BM / 2) + mg * 16 + quad * 4;
#pragma unroll
            for (int j = 0; j < 4; ++j) {
                long c = col0 + wn * 64 + (j >> 1) * 32 + (j & 1) * 16 + l16;
#pragma unroll
                for (int reg = 0; reg < 4; ++reg)
                    Fout[(r + reg) * Nn + c] = acc[mg][j][reg];
            }
        }
    } else {
        const int bx = blockIdx.x;
        if (bx == 9) {
            // V heads (cols 2304..2559, unpermuted): bias only
#pragma unroll
            for (int mg = 0; mg < 2 * MFH; ++mg) {
                long r = row0 + wm * 128 + mg * 16 + quad * 4;
#pragma unroll
                for (int j = 0; j < 4; ++j) {
                    int ctc = wn * 64 + (j >> 1) * 32 + (j & 1) * 16 + l16;
                    float bv = bias[2304 + ctc];
#pragma unroll
                    for (int reg = 0; reg < 4; ++reg)
                        Vtmp[(r + reg) * 256 + ctc] =
                            __float2bfloat16(acc[mg][j][reg] + bv);
                }
            }
        } else {
            // Q (bx<8) or K (bx==8) heads, phi-permuted cols:
            // acc[mg][ni] pairs acc[mg][ni+2]; i = (wn&1)*32 + ni*16 + l16
            const bool isQ = (bx < 8);
            const int head = bx * 2 + (wn >> 1);
            float invf[2];
#pragma unroll
            for (int ni = 0; ni < 2; ++ni) {
                int i = (wn & 1) * 32 + ni * 16 + l16;
                invf[ni] = __expf(-(float)i * (13.815510557964274f / 64.0f));
            }
#pragma unroll
            for (int mg = 0; mg < 2 * MFH; ++mg) {
                long r0r = row0 + wm * 128 + mg * 16 + quad * 4;
#pragma unroll
                for (int reg = 0; reg < 4; ++reg) {
                    long rr = r0r + reg;
                    int b = (int)(rr >> 11), s = (int)(rr & 2047);
                    float p = (float)pos[rr];
#pragma unroll
                    for (int ni = 0; ni < 2; ++ni) {
                        int i = (wn & 1) * 32 + ni * 16 + l16;
                        float x1 = acc[mg][ni][reg]     + bias[head * 128 + i];
                        float x2 = acc[mg][ni + 2][reg] + bias[head * 128 + i + 64];
                        float sn, cs;
                        __sincosf(p * invf[ni], &sn, &cs);
                        float o1 = x1 * cs - x2 * sn;
                        float o2 = x2 * cs + x1 * sn;
                        if (isQ) {
                            long ob = (((long)b * NH_ + head) * S_ + s) * HD_;
                            Qr[ob + i]      = __float2bfloat16(o1 * QSCALE_);
                            Qr[ob + i + 64] = __float2bfloat16(o2 * QSCALE_);
                        } else {
                            long ob = (((long)b * NKV_ + (head - 16)) * S_ + s) * HD_;
                            Kr[ob + i]      = __float2bfloat16(o1);
                            Kr[ob + i + 64] = __float2bfloat16(o2);
                        }
                    }
                }
            }
        }
    }
}

// ---------------------------------------------------------------------------
// Causal GQA flash attention, 32x32x16 MFMA, 128q x 64k tiles, 4 waves.
// (unchanged this round)
__global__ __launch_bounds__(256) void attn_kernel(
    const bf16* __restrict__ Q,   // [B][NH][S][HD], pre-scaled by SCALE*log2e
    const bf16* __restrict__ Kk,  // [B][NKV][S][HD]
    const bf16* __restrict__ Vt,  // [B][NKV*HD][sigma(S)]
    bf16* __restrict__ O)         // [B][S][NH*HD]
{
    const int id = blockIdx.x;
    const int hb = id & 31;
    const int h = hb & 15, b = hb >> 4;
    const int q4 = (id >> 5) & 7, hi = id >> 8;
    const int qtile = hi ? (15 - q4) : q4;    // co-resident pair sums to 15
    const int kvh = h >> 3;
    const int tid = threadIdx.x, wave = tid >> 6, lane = tid & 63;
    const int l31 = lane & 31, half = lane >> 5;
    const int qh = wave;                      // q rows qh*32..+31

    __shared__ __align__(16) char smem[64 * 1024];
    __shared__ float Ls[128];

    const bf16* Kbase = Kk + ((long)(b * NKV_ + kvh) * S_) * HD_;
    const bf16* Vbase = Vt + ((long)b * (2 * HD_) + kvh * HD_) * (long)S_;

    // stage all 128 Q rows (32 KB across both halves of buf0), hoist B-frags
    const bf16* Qg = Q + (((long)(b * NH_ + h) * S_) + qtile * 128) * HD_;
    bf16* Qs = (bf16*)smem;
#pragma unroll
    for (int i = 0; i < 8; i++) {
        int cb = i * 256 + wave * 64;
        int c = cb + lane, r = c >> 4, sc = c & 15;
        async_load16(Qg + r * HD_ + (sc ^ (r & 15)) * 8, Qs + (size_t)cb * 8);
    }
    __syncthreads();
    bf16x8 qf[8];
#pragma unroll
    for (int ks = 0; ks < 8; ks++) {
        int gc = 2 * ks + half;
        qf[ks] = *(const bf16x8*)(Qs + (qh * 32 + l31) * 128 +
                                  ((gc ^ (l31 & 15)) * 8));
    }
    __syncthreads();   // smem now reusable for K/V tiles

    f32x16 acc_o[4];
#pragma unroll
    for (int r = 0; r < 16; r++) {
        acc_o[0][r] = 0.f; acc_o[1][r] = 0.f;
        acc_o[2][r] = 0.f; acc_o[3][r] = 0.f;
    }
    float lsum = 0.f;

    const int qc32 = qtile * 4 + qh;          // this wave's 32-q chunk index
    const int kt_max = 2 * qtile + 1;

    // prologue: issue kt=0 into buf 0
    {
        bf16* KsW  = (bf16*)smem;
        bf16* VtsW = (bf16*)(smem + 16384);
#pragma unroll
        for (int i = 0; i < 4; i++) {
            int cb = i * 256 + wave * 64;
            int c = cb + lane, r = c >> 4, sc = c & 15;
            async_load16(Kbase + r * HD_ + (sc ^ (r & 15)) * 8,
                         KsW + (size_t)cb * 8);
        }
#pragma unroll
        for (int i = 0; i < 4; i++) {
            int cb = i * 256 + wave * 64;
            int c = cb + lane, r = c >> 3, sc = c & 7;
            async_load16(Vbase + (long)r * S_ + (sc ^ (r & 7)) * 8,
                         VtsW + (size_t)cb * 8);
        }
    }

#pragma unroll 1
    for (int kt = 0; kt <= kt_max; kt++) {
        __syncthreads();   // buf[kt&1] complete; prev compute done everywhere
        const bf16* Ks  = (const bf16*)(smem + (kt & 1) * 32768);
        const bf16* Vts = (const bf16*)(smem + (kt & 1) * 32768 + 16384);

        if (kt < kt_max) {   // prefetch kt+1 into the other buffer
            bf16* KsW  = (bf16*)(smem + ((kt + 1) & 1) * 32768);
            bf16* VtsW = (bf16*)(smem + ((kt + 1) & 1) * 32768 + 16384);
            const bf16* Kg = Kbase + (long)(kt + 1) * 64 * HD_;
#pragma unroll
            for (int i = 0; i < 4; i++) {
                int cb = i * 256 + wave * 64;
                int c = cb + lane, r = c >> 4, sc = c & 15;
                async_load16(Kg + r * HD_ + (sc ^ (r & 15)) * 8,
                             KsW + (size_t)cb * 8);
            }
            const bf16* Vg = Vbase + (kt + 1) * 64;
#pragma unroll
            for (int i = 0; i < 4; i++) {
                int cb = i * 256 + wave * 64;
                int c = cb + lane, r = c >> 3, sc = c & 7;
                async_load16(Vg + (long)r * S_ + (sc ^ (r & 7)) * 8,
                             VtsW + (size_t)cb * 8);
            }
        }

#pragma unroll
        for (int mh = 0; mh < 2; mh++) {
            const int kc32 = 2 * kt + mh;
            if (kc32 > qc32) continue;        // fully masked subtile (wave-uniform)

            // St = K Q^T : D[m=key][n=q], 32 keys x this wave's 32 q
            f32x16 st;
#pragma unroll
            for (int r = 0; r < 16; r++) st[r] = 0.f;
#pragma unroll
            for (int ks = 0; ks < 8; ks++) {
                int gc = 2 * ks + half;
                bf16x8 ka = *(const bf16x8*)(Ks + (mh * 32 + l31) * 128 +
                                             ((gc ^ (l31 & 15)) * 8));
                st = __builtin_amdgcn_mfma_f32_32x32x16_bf16(ka, qf[ks], st, 0, 0, 0);
            }

            // p = exp2(st); triangular mask when key-chunk == q-chunk.
            const bool tri = (kc32 == qc32);
            bf16x8 pa[2];
#pragma unroll
            for (int t = 0; t < 2; t++)
#pragma unroll
                for (int j = 0; j < 8; j++) {
                    int r = t * 8 + j;
                    int krow = (r & 3) + 8 * (r >> 2) + 4 * half;
                    float x = st[r];
                    if (tri && krow > l31) x = -1e30f;
                    float pv = __builtin_amdgcn_exp2f(x);
                    lsum += pv;               // lane l31 = q here
                    pa[t][j] = f2bf(pv);
                }

            // O += P V (all 128 dims)
#pragma unroll
            for (int t = 0; t < 2; t++) {
                int gc = 4 * mh + 2 * t + half;
#pragma unroll
                for (int nt = 0; nt < 4; nt++) {
                    bf16x8 vb = *(const bf16x8*)(Vts + (nt * 32 + l31) * 64 +
                                                 ((gc ^ (l31 & 7)) * 8));
                    acc_o[nt] = __builtin_amdgcn_mfma_f32_32x32x16_bf16(
                        pa[t], vb, acc_o[nt], 0, 0, 0);
                }
            }
        }
    }

    // row-sum broadcast: lsum indexed by lane=q; acc_o rows are reg-indexed q.
    float ltot = lsum + __shfl_xor(lsum, 32);
    __syncthreads();   // all compute done before Ls write
    if (half == 0) Ls[qh * 32 + l31] = ltot;
    __syncthreads();

    float inv_l[16];
#pragma unroll
    for (int r = 0; r < 16; r++) {
        int qrow = (r & 3) + 8 * (r >> 2) + 4 * half;
        inv_l[r] = __builtin_amdgcn_rcpf(Ls[qh * 32 + qrow]);
    }
#pragma unroll
    for (int nt = 0; nt < 4; nt++)
#pragma unroll
        for (int r = 0; r < 16; r++) {
            int qrow = (r & 3) + 8 * (r >> 2) + 4 * half;
            float v = acc_o[nt][r] * inv_l[r];
            O[((long)b * S_ + qtile * 128 + qh * 32 + qrow) * (NH_ * HD_) +
              h * HD_ + nt * 32 + l31] = __float2bfloat16(v);
        }
}

// ---------------------------------------------------------------------------
extern "C" void kernel_launch(void* const* d_in, const int* in_sizes, int n_in,
                              void* d_out, int out_size, void* d_ws, size_t ws_size,
                              hipStream_t stream) {
    const int*   pos  = (const int*)d_in[0];
    const float* X    = (const float*)d_in[1];
    const float* Wqkv = (const float*)d_in[2];
    const float* bqkv = (const float*)d_in[3];
    const float* Wo   = (const float*)d_in[4];
    float* out = (float*)d_out;

    char* ws = (char*)d_ws;
    bf16* Xb    = (bf16*)ws;  ws += (size_t)B_ * S_ * HID_ * 2;
    bf16* Wqkvt = (bf16*)ws;  ws += (size_t)QKV_N * HID_ * 2;
    bf16* Wot   = (bf16*)ws;  ws += (size_t)HID_ * HID_ * 2;
    bf16* Qr    = (bf16*)ws;  ws += (size_t)B_ * NH_ * S_ * HD_ * 2;
    bf16* Kr    = (bf16*)ws;  ws += (size_t)B_ * NKV_ * S_ * HD_ * 2;
    bf16* Vtmp  = (bf16*)ws;  ws += (size_t)B_ * S_ * 2 * HD_ * 2;
    bf16* VtG   = (bf16*)ws;  ws += (size_t)B_ * NKV_ * HD_ * S_ * 2;
    bf16* AO    = (bf16*)ws;  ws += (size_t)B_ * S_ * NH_ * HD_ * 2;

    // one-time: allow >64KB dynamic LDS for the pipelined GEMM cores
    static bool attr_done = false;
    if (!attr_done) {
        hipFuncSetAttribute(reinterpret_cast<const void*>(&gemm_core<256, 1>),
                            hipFuncAttributeMaxDynamicSharedMemorySize, 131072);
        hipFuncSetAttribute(reinterpret_cast<const void*>(&gemm_core<128, 0>),
                            hipFuncAttributeMaxDynamicSharedMemorySize, 98304);
        attr_done = true;
    }

    // 1. fused cast + weight transposes (Wqkvt phi-permuted)
    prep1<<<17408, 256, 0, stream>>>(X, Xb, Wqkv, Wqkvt, Wo, Wot);

    // 2. QKV projection + bias + RoPE fused epilogue (256x256 tiles, 160 wg)
    gemm_core<256, 1><<<dim3(QKV_N / 256, (B_ * S_) / 256), 512, 131072, stream>>>(
        Xb, Wqkvt, bqkv, pos, Qr, Kr, Vtmp, nullptr, 0);

    // 3. V transpose (sigma key permutation)
    v_transpose<<<1024, 256, 0, stream>>>(Vtmp, VtG);

    // 4. causal GQA attention (512 blocks, 128q tiles, balanced qtile swizzle)
    attn_kernel<<<dim3(512), 256, 0, stream>>>(Qr, Kr, VtG, AO);

    // 5. output projection (128x256 tiles -> 256 wg = perfect CU fill)
    gemm_core<128, 0><<<dim3(HID_ / 256, (B_ * S_) / 128), 512, 98304, stream>>>(
        AO, Wot, nullptr, nullptr, nullptr, nullptr, nullptr, out, HID_);
}

// Round 4
// 258.847 us; speedup vs baseline: 1.9016x; 1.9016x over previous
//
#include <hip/hip_runtime.h>
#include <hip/hip_bf16.h>
#include <stdint.h>

typedef __hip_bfloat16 bf16;
typedef __attribute__((ext_vector_type(4))) float f32x4;
typedef __attribute__((ext_vector_type(16))) float f32x16;
typedef __attribute__((ext_vector_type(8))) short bf16x8;

#define B_  2
#define S_  2048
#define HID_ 2048
#define NH_ 16
#define NKV_ 2
#define HD_ 128
#define QKV_N 2560           // (NH + 2*NKV) * HD
// SCALE * log2(e): scores in log2 domain so softmax exp is v_exp_f32
#define QSCALE_ (0.08838834764831845f * 1.4426950408889634f)

__device__ __forceinline__ void async_load16(const void* g, void* l) {
    __builtin_amdgcn_global_load_lds(
        (const __attribute__((address_space(1))) unsigned int*)(uintptr_t)g,
        (__attribute__((address_space(3))) unsigned int*)(uintptr_t)l,
        16, 0, 0);
}

__device__ __forceinline__ short f2bf(float f) {
    __hip_bfloat16 h = __float2bfloat16(f);
    return *reinterpret_cast<short*>(&h);
}

// ---------------------------------------------------------------------------
// prep1: fused X cast + Wqkv transpose-cast (phi-permuted) + Wo transpose-cast
// phi swaps bits 5<->6 of the within-head (128) column for Q/K heads so RoPE
// pairs (i, i+64) land in the same lane of the QKV gemm epilogue. Involution.
__global__ void prep1(const float* __restrict__ X, bf16* __restrict__ Xb,
                      const float* __restrict__ Wqkv, bf16* __restrict__ Wqkvt,
                      const float* __restrict__ Wo, bf16* __restrict__ Wot)
{
    __shared__ float t[32][33];
    int bid = blockIdx.x;
    if (bid < 8192) {
        long idx = ((long)bid * 256 + threadIdx.x) * 4;
        float4 v = *(const float4*)(X + idx);
        bf16 o[4];
        o[0] = __float2bfloat16(v.x); o[1] = __float2bfloat16(v.y);
        o[2] = __float2bfloat16(v.z); o[3] = __float2bfloat16(v.w);
        *(ulong1*)(Xb + idx) = *(ulong1*)o;
        return;
    }
    const float* in; bf16* out; int R, C, bx, by; bool perm;
    if (bid < 13312) {
        int v = bid - 8192;          // (80, 64)
        bx = v % 80; by = v / 80;
        in = Wqkv; out = Wqkvt; R = HID_; C = QKV_N; perm = true;
    } else {
        int v = bid - 13312;         // (64, 64)
        bx = v & 63; by = v >> 6;
        in = Wo; out = Wot; R = HID_; C = HID_; perm = false;
    }
    int tx = threadIdx.x & 31, ty = threadIdx.x >> 5;   // 32x8
    int c = bx * 32 + tx;
#pragma unroll
    for (int j = 0; j < 4; j++) {
        int r = by * 32 + ty + j * 8;
        t[ty + j * 8][tx] = in[(long)r * C + c];
    }
    __syncthreads();
#pragma unroll
    for (int j = 0; j < 4; j++) {
        int cc = bx * 32 + ty + j * 8;
        int rr = by * 32 + tx;
        int ccp = cc;
        if (perm && cc < (NH_ + NKV_) * HD_)   // Q/K heads: swap bits 5,6
            ccp = (cc & ~0x60) | ((cc & 0x20) << 1) | ((cc & 0x40) >> 1);
        out[(long)ccp * R + rr] = __float2bfloat16(t[tx][ty + j * 8]);
    }
}

// ---------------------------------------------------------------------------
// v_transpose: Vtmp[b][s][j] (bias already applied) -> VtG[b][j][sigma(s)],
// sigma = swap bits 2<->3 of s (PV A-fragment key ordering).
__global__ void v_transpose(const bf16* __restrict__ Vtmp, bf16* __restrict__ VtG) {
    __shared__ bf16 t[32][33];
    int v = blockIdx.x;                       // (8, 64, 2) flattened
    int j0 = (v & 7) * 32;
    int s0 = ((v >> 3) & 63) * 32;
    int b = v >> 9;
    int tx = threadIdx.x & 31, ty = threadIdx.x >> 5;   // 32x8
#pragma unroll
    for (int jj = 0; jj < 4; jj++) {
        int s = s0 + ty + jj * 8;
        t[ty + jj * 8][tx] = Vtmp[((long)b * S_ + s) * 256 + j0 + tx];
    }
    __syncthreads();
    int txp = (tx & 0x13) | ((tx & 4) << 1) | ((tx & 8) >> 1);  // swap bits 2,3
#pragma unroll
    for (int jj = 0; jj < 4; jj++) {
        int j = j0 + ty + jj * 8;
        VtG[((long)b * (2 * HD_) + j) * S_ + s0 + txp] = t[tx][ty + jj * 8];
    }
}

// ---------------------------------------------------------------------------
// QKV GEMM with fused bias + RoPE epilogue. 128x128 tile, BK=64.
// XCD-chunked swizzle (T1): grid 20x32 = 640 = 8*80 blocks; each XCD gets
// 80 contiguous logical tiles = 4 M-rows x 20 col-tiles -> B-panels are
// fetched once per XCD (L2-local) instead of once per M-row.
__global__ __launch_bounds__(256, 3) void gemm_qkv(
    const bf16* __restrict__ A, const bf16* __restrict__ Bt,
    const float* __restrict__ bias, const int* __restrict__ pos,
    bf16* __restrict__ Qr, bf16* __restrict__ Kr, bf16* __restrict__ Vtmp)
{
    __shared__ __align__(16) bf16 As[128 * 64];
    __shared__ __align__(16) bf16 Bs[128 * 64];
    const int K = HID_;
    const int tid = threadIdx.x;
    const int wave = tid >> 6, lane = tid & 63;
    const int quad = lane >> 4, l16 = lane & 15;
    const int wr = wave >> 1, wc = wave & 1;

    // T1 XCD swizzle: bijective since nwg % 8 == 0
    const int nwg  = gridDim.x * gridDim.y;
    const int orig = blockIdx.y * gridDim.x + blockIdx.x;
    const int swz  = (orig & 7) * (nwg >> 3) + (orig >> 3);
    const int bx = swz % gridDim.x, by = swz / gridDim.x;

    const long row0 = (long)by * 128;
    const long col0 = (long)bx * 128;

    f32x4 acc[4][4];
#pragma unroll
    for (int i = 0; i < 4; i++)
#pragma unroll
        for (int j = 0; j < 4; j++) acc[i][j] = {0.f, 0.f, 0.f, 0.f};

    for (int k0 = 0; k0 < K; k0 += 64) {
        __syncthreads();
#pragma unroll
        for (int i = 0; i < 4; i++) {
            int cb = i * 256 + wave * 64;
            int c = cb + lane;
            int r = c >> 3, sc = c & 7;
            int gc = sc ^ (r & 7);
            async_load16(A + (row0 + r) * K + k0 + gc * 8, As + (size_t)cb * 8);
            async_load16(Bt + (col0 + r) * K + k0 + gc * 8, Bs + (size_t)cb * 8);
        }
        __syncthreads();

#pragma unroll
        for (int ks2 = 0; ks2 < 2; ks2++) {
            const int slot = ((ks2 * 4 + quad) ^ (l16 & 7)) * 8;
            bf16x8 af[4], bfr[4];
#pragma unroll
            for (int mi = 0; mi < 4; mi++)
                af[mi] = *(const bf16x8*)(As + (wr * 64 + mi * 16 + l16) * 64 + slot);
#pragma unroll
            for (int ni = 0; ni < 4; ni++)
                bfr[ni] = *(const bf16x8*)(Bs + (wc * 64 + ni * 16 + l16) * 64 + slot);
#pragma unroll
            for (int mi = 0; mi < 4; mi++)
#pragma unroll
                for (int ni = 0; ni < 4; ni++)
                    acc[mi][ni] = __builtin_amdgcn_mfma_f32_16x16x32_bf16(
                        af[mi], bfr[ni], acc[mi][ni], 0, 0, 0);
        }
    }

    const int ct = bx;
    if (ct < NH_ + NKV_) {
        // RoPE heads (Q or K)
        const bool isQ = (ct < NH_);
        float invf[2];
#pragma unroll
        for (int np = 0; np < 2; np++) {
            int i = wc * 32 + np * 16 + l16;
            invf[np] = __expf(-(float)i * (13.815510557964274f / 64.0f));
        }
#pragma unroll
        for (int mi = 0; mi < 4; mi++) {
            long r0 = row0 + wr * 64 + mi * 16 + quad * 4;
#pragma unroll
            for (int reg = 0; reg < 4; reg++) {
                long rr = r0 + reg;
                int b = (int)(rr >> 11), s = (int)(rr & 2047);
                float p = (float)pos[rr];
#pragma unroll
                for (int np = 0; np < 2; np++) {
                    int i = wc * 32 + np * 16 + l16;
                    float x1 = acc[mi][np][reg]     + bias[ct * 128 + i];
                    float x2 = acc[mi][np + 2][reg] + bias[ct * 128 + i + 64];
                    float sn, cs;
                    __sincosf(p * invf[np], &sn, &cs);
                    float o1 = x1 * cs - x2 * sn;
                    float o2 = x2 * cs + x1 * sn;
                    if (isQ) {
                        long ob = (((long)b * NH_ + ct) * S_ + s) * HD_;
                        Qr[ob + i]      = __float2bfloat16(o1 * QSCALE_);
                        Qr[ob + i + 64] = __float2bfloat16(o2 * QSCALE_);
                    } else {
                        long ob = (((long)b * NKV_ + (ct - NH_)) * S_ + s) * HD_;
                        Kr[ob + i]      = __float2bfloat16(o1);
                        Kr[ob + i + 64] = __float2bfloat16(o2);
                    }
                }
            }
        }
    } else {
        // V heads: bias only, natural [b*S+s][256] layout
#pragma unroll
        for (int mi = 0; mi < 4; mi++) {
            long r0 = row0 + wr * 64 + mi * 16 + quad * 4;
#pragma unroll
            for (int ni = 0; ni < 4; ni++) {
                int c = wc * 64 + ni * 16 + l16;
                float bv = bias[ct * 128 + c];
#pragma unroll
                for (int reg = 0; reg < 4; reg++)
                    Vtmp[(r0 + reg) * 256 + (ct - 18) * 128 + c] =
                        __float2bfloat16(acc[mi][ni][reg] + bv);
            }
        }
    }
}

// ---------------------------------------------------------------------------
// Output projection GEMM: 128x128 tile, BK=64, fp32 out. T1 swizzle (512=8*64).
__global__ __launch_bounds__(256, 3) void gemm_out(
    const bf16* __restrict__ A, const bf16* __restrict__ Bt,
    float* __restrict__ Cout, int M, int N, int K)
{
    __shared__ __align__(16) bf16 As[128 * 64];
    __shared__ __align__(16) bf16 Bs[128 * 64];
    const int tid = threadIdx.x;
    const int wave = tid >> 6, lane = tid & 63;
    const int quad = lane >> 4, l16 = lane & 15;
    const int wr = wave >> 1, wc = wave & 1;

    // T1 XCD swizzle: bijective since nwg % 8 == 0
    const int nwg  = gridDim.x * gridDim.y;
    const int orig = blockIdx.y * gridDim.x + blockIdx.x;
    const int swz  = (orig & 7) * (nwg >> 3) + (orig >> 3);
    const int bx = swz % gridDim.x, by = swz / gridDim.x;

    const long row0 = (long)by * 128;
    const long col0 = (long)bx * 128;

    f32x4 acc[4][4];
#pragma unroll
    for (int i = 0; i < 4; i++)
#pragma unroll
        for (int j = 0; j < 4; j++) acc[i][j] = {0.f, 0.f, 0.f, 0.f};

    for (int k0 = 0; k0 < K; k0 += 64) {
        __syncthreads();
#pragma unroll
        for (int i = 0; i < 4; i++) {
            int cb = i * 256 + wave * 64;
            int c = cb + lane;
            int r = c >> 3, sc = c & 7;
            int gc = sc ^ (r & 7);
            async_load16(A + (row0 + r) * K + k0 + gc * 8, As + (size_t)cb * 8);
            async_load16(Bt + (col0 + r) * K + k0 + gc * 8, Bs + (size_t)cb * 8);
        }
        __syncthreads();

#pragma unroll
        for (int ks2 = 0; ks2 < 2; ks2++) {
            const int slot = ((ks2 * 4 + quad) ^ (l16 & 7)) * 8;
            bf16x8 af[4], bfr[4];
#pragma unroll
            for (int mi = 0; mi < 4; mi++)
                af[mi] = *(const bf16x8*)(As + (wr * 64 + mi * 16 + l16) * 64 + slot);
#pragma unroll
            for (int ni = 0; ni < 4; ni++)
                bfr[ni] = *(const bf16x8*)(Bs + (wc * 64 + ni * 16 + l16) * 64 + slot);
#pragma unroll
            for (int mi = 0; mi < 4; mi++)
#pragma unroll
                for (int ni = 0; ni < 4; ni++)
                    acc[mi][ni] = __builtin_amdgcn_mfma_f32_16x16x32_bf16(
                        af[mi], bfr[ni], acc[mi][ni], 0, 0, 0);
        }
    }

#pragma unroll
    for (int mi = 0; mi < 4; mi++) {
        long r = row0 + wr * 64 + mi * 16 + quad * 4;
#pragma unroll
        for (int ni = 0; ni < 4; ni++) {
            long c = col0 + wc * 64 + ni * 16 + l16;
#pragma unroll
            for (int reg = 0; reg < 4; reg++)
                Cout[(r + reg) * N + c] = acc[mi][ni][reg];
        }
    }
}

// ---------------------------------------------------------------------------
// Causal GQA flash attention, 32x32x16 MFMA, 128q x 64k tiles, 4 waves.
// Double-buffered K/V staging. T5: setprio(1) around MFMA clusters.
__global__ __launch_bounds__(256) void attn_kernel(
    const bf16* __restrict__ Q,   // [B][NH][S][HD], pre-scaled by SCALE*log2e
    const bf16* __restrict__ Kk,  // [B][NKV][S][HD]
    const bf16* __restrict__ Vt,  // [B][NKV*HD][sigma(S)]
    bf16* __restrict__ O)         // [B][S][NH*HD]
{
    const int id = blockIdx.x;
    const int hb = id & 31;
    const int h = hb & 15, b = hb >> 4;
    const int q4 = (id >> 5) & 7, hi = id >> 8;
    const int qtile = hi ? (15 - q4) : q4;    // co-resident pair sums to 15
    const int kvh = h >> 3;
    const int tid = threadIdx.x, wave = tid >> 6, lane = tid & 63;
    const int l31 = lane & 31, half = lane >> 5;
    const int qh = wave;                      // q rows qh*32..+31

    __shared__ __align__(16) char smem[64 * 1024];
    __shared__ float Ls[128];

    const bf16* Kbase = Kk + ((long)(b * NKV_ + kvh) * S_) * HD_;
    const bf16* Vbase = Vt + ((long)b * (2 * HD_) + kvh * HD_) * (long)S_;

    // stage all 128 Q rows (32 KB across both halves of buf0), hoist B-frags
    const bf16* Qg = Q + (((long)(b * NH_ + h) * S_) + qtile * 128) * HD_;
    bf16* Qs = (bf16*)smem;
#pragma unroll
    for (int i = 0; i < 8; i++) {
        int cb = i * 256 + wave * 64;
        int c = cb + lane, r = c >> 4, sc = c & 15;
        async_load16(Qg + r * HD_ + (sc ^ (r & 15)) * 8, Qs + (size_t)cb * 8);
    }
    __syncthreads();
    bf16x8 qf[8];
#pragma unroll
    for (int ks = 0; ks < 8; ks++) {
        int gc = 2 * ks + half;
        qf[ks] = *(const bf16x8*)(Qs + (qh * 32 + l31) * 128 +
                                  ((gc ^ (l31 & 15)) * 8));
    }
    __syncthreads();   // smem now reusable for K/V tiles

    f32x16 acc_o[4];
#pragma unroll
    for (int r = 0; r < 16; r++) {
        acc_o[0][r] = 0.f; acc_o[1][r] = 0.f;
        acc_o[2][r] = 0.f; acc_o[3][r] = 0.f;
    }
    float lsum = 0.f;

    const int qc32 = qtile * 4 + qh;          // this wave's 32-q chunk index
    const int kt_max = 2 * qtile + 1;

    // prologue: issue kt=0 into buf 0
    {
        bf16* KsW  = (bf16*)smem;
        bf16* VtsW = (bf16*)(smem + 16384);
#pragma unroll
        for (int i = 0; i < 4; i++) {
            int cb = i * 256 + wave * 64;
            int c = cb + lane, r = c >> 4, sc = c & 15;
            async_load16(Kbase + r * HD_ + (sc ^ (r & 15)) * 8,
                         KsW + (size_t)cb * 8);
        }
#pragma unroll
        for (int i = 0; i < 4; i++) {
            int cb = i * 256 + wave * 64;
            int c = cb + lane, r = c >> 3, sc = c & 7;
            async_load16(Vbase + (long)r * S_ + (sc ^ (r & 7)) * 8,
                         VtsW + (size_t)cb * 8);
        }
    }

#pragma unroll 1
    for (int kt = 0; kt <= kt_max; kt++) {
        __syncthreads();   // buf[kt&1] complete; prev compute done everywhere
        const bf16* Ks  = (const bf16*)(smem + (kt & 1) * 32768);
        const bf16* Vts = (const bf16*)(smem + (kt & 1) * 32768 + 16384);

        if (kt < kt_max) {   // prefetch kt+1 into the other buffer
            bf16* KsW  = (bf16*)(smem + ((kt + 1) & 1) * 32768);
            bf16* VtsW = (bf16*)(smem + ((kt + 1) & 1) * 32768 + 16384);
            const bf16* Kg = Kbase + (long)(kt + 1) * 64 * HD_;
#pragma unroll
            for (int i = 0; i < 4; i++) {
                int cb = i * 256 + wave * 64;
                int c = cb + lane, r = c >> 4, sc = c & 15;
                async_load16(Kg + r * HD_ + (sc ^ (r & 15)) * 8,
                             KsW + (size_t)cb * 8);
            }
            const bf16* Vg = Vbase + (kt + 1) * 64;
#pragma unroll
            for (int i = 0; i < 4; i++) {
                int cb = i * 256 + wave * 64;
                int c = cb + lane, r = c >> 3, sc = c & 7;
                async_load16(Vg + (long)r * S_ + (sc ^ (r & 7)) * 8,
                             VtsW + (size_t)cb * 8);
            }
        }

#pragma unroll
        for (int mh = 0; mh < 2; mh++) {
            const int kc32 = 2 * kt + mh;
            if (kc32 > qc32) continue;        // fully masked subtile (wave-uniform)

            // St = K Q^T : D[m=key][n=q], 32 keys x this wave's 32 q
            f32x16 st;
#pragma unroll
            for (int r = 0; r < 16; r++) st[r] = 0.f;
            __builtin_amdgcn_s_setprio(1);
#pragma unroll
            for (int ks = 0; ks < 8; ks++) {
                int gc = 2 * ks + half;
                bf16x8 ka = *(const bf16x8*)(Ks + (mh * 32 + l31) * 128 +
                                             ((gc ^ (l31 & 15)) * 8));
                st = __builtin_amdgcn_mfma_f32_32x32x16_bf16(ka, qf[ks], st, 0, 0, 0);
            }
            __builtin_amdgcn_s_setprio(0);

            // p = exp2(st); triangular mask when key-chunk == q-chunk.
            // C-layout: col=q=l31, row=key=(r&3)+8*(r>>2)+4*half.
            const bool tri = (kc32 == qc32);
            bf16x8 pa[2];
#pragma unroll
            for (int t = 0; t < 2; t++)
#pragma unroll
                for (int j = 0; j < 8; j++) {
                    int r = t * 8 + j;
                    int krow = (r & 3) + 8 * (r >> 2) + 4 * half;
                    float x = st[r];
                    if (tri && krow > l31) x = -1e30f;
                    float pv = __builtin_amdgcn_exp2f(x);
                    lsum += pv;               // lane l31 = q here
                    pa[t][j] = f2bf(pv);
                }

            // O += P V (all 128 dims)
            __builtin_amdgcn_s_setprio(1);
#pragma unroll
            for (int t = 0; t < 2; t++) {
                int gc = 4 * mh + 2 * t + half;
#pragma unroll
                for (int nt = 0; nt < 4; nt++) {
                    bf16x8 vb = *(const bf16x8*)(Vts + (nt * 32 + l31) * 64 +
                                                 ((gc ^ (l31 & 7)) * 8));
                    acc_o[nt] = __builtin_amdgcn_mfma_f32_32x32x16_bf16(
                        pa[t], vb, acc_o[nt], 0, 0, 0);
                }
            }
            __builtin_amdgcn_s_setprio(0);
        }
    }

    // row-sum broadcast: lsum indexed by lane=q; acc_o rows are reg-indexed q.
    float ltot = lsum + __shfl_xor(lsum, 32);
    __syncthreads();   // all compute done before Ls write
    if (half == 0) Ls[qh * 32 + l31] = ltot;
    __syncthreads();

    float inv_l[16];
#pragma unroll
    for (int r = 0; r < 16; r++) {
        int qrow = (r & 3) + 8 * (r >> 2) + 4 * half;
        inv_l[r] = __builtin_amdgcn_rcpf(Ls[qh * 32 + qrow]);
    }
#pragma unroll
    for (int nt = 0; nt < 4; nt++)
#pragma unroll
        for (int r = 0; r < 16; r++) {
            int qrow = (r & 3) + 8 * (r >> 2) + 4 * half;
            float v = acc_o[nt][r] * inv_l[r];
            O[((long)b * S_ + qtile * 128 + qh * 32 + qrow) * (NH_ * HD_) +
              h * HD_ + nt * 32 + l31] = __float2bfloat16(v);
        }
}

// ---------------------------------------------------------------------------
extern "C" void kernel_launch(void* const* d_in, const int* in_sizes, int n_in,
                              void* d_out, int out_size, void* d_ws, size_t ws_size,
                              hipStream_t stream) {
    const int*   pos  = (const int*)d_in[0];
    const float* X    = (const float*)d_in[1];
    const float* Wqkv = (const float*)d_in[2];
    const float* bqkv = (const float*)d_in[3];
    const float* Wo   = (const float*)d_in[4];
    float* out = (float*)d_out;

    char* ws = (char*)d_ws;
    bf16* Xb    = (bf16*)ws;  ws += (size_t)B_ * S_ * HID_ * 2;
    bf16* Wqkvt = (bf16*)ws;  ws += (size_t)QKV_N * HID_ * 2;
    bf16* Wot   = (bf16*)ws;  ws += (size_t)HID_ * HID_ * 2;
    bf16* Qr    = (bf16*)ws;  ws += (size_t)B_ * NH_ * S_ * HD_ * 2;
    bf16* Kr    = (bf16*)ws;  ws += (size_t)B_ * NKV_ * S_ * HD_ * 2;
    bf16* Vtmp  = (bf16*)ws;  ws += (size_t)B_ * S_ * 2 * HD_ * 2;
    bf16* VtG   = (bf16*)ws;  ws += (size_t)B_ * NKV_ * HD_ * S_ * 2;
    bf16* AO    = (bf16*)ws;  ws += (size_t)B_ * S_ * NH_ * HD_ * 2;

    // 1. fused cast + weight transposes (Wqkvt phi-permuted)
    prep1<<<17408, 256, 0, stream>>>(X, Xb, Wqkv, Wqkvt, Wo, Wot);

    // 2. QKV projection + bias + RoPE fused epilogue (640 blocks, T1 swizzle)
    gemm_qkv<<<dim3(QKV_N / 128, (B_ * S_) / 128), 256, 0, stream>>>(
        Xb, Wqkvt, bqkv, pos, Qr, Kr, Vtmp);

    // 3. V transpose (sigma key permutation)
    v_transpose<<<1024, 256, 0, stream>>>(Vtmp, VtG);

    // 4. causal GQA attention (512 blocks, 128q tiles, balanced qtile swizzle)
    attn_kernel<<<dim3(512), 256, 0, stream>>>(Qr, Kr, VtG, AO);

    // 5. output projection (512 blocks, T1 swizzle, fp32 out)
    gemm_out<<<dim3(HID_ / 128, (B_ * S_) / 128), 256, 0, stream>>>(
        AO, Wot, out, B_ * S_, HID_, HID_);
}

// Round 5
// 258.082 us; speedup vs baseline: 1.9073x; 1.0030x over previous
//
#include <hip/hip_runtime.h>
#include <hip/hip_bf16.h>
#include <stdint.h>

typedef __hip_bfloat16 bf16;
typedef __attribute__((ext_vector_type(4))) float f32x4;
typedef __attribute__((ext_vector_type(16))) float f32x16;
typedef __attribute__((ext_vector_type(8))) short bf16x8;

#define B_  2
#define S_  2048
#define HID_ 2048
#define NH_ 16
#define NKV_ 2
#define HD_ 128
#define QKV_N 2560           // (NH + 2*NKV) * HD
// SCALE * log2(e): scores in log2 domain so softmax exp is v_exp_f32
#define QSCALE_ (0.08838834764831845f * 1.4426950408889634f)

__device__ __forceinline__ void async_load16(const void* g, void* l) {
    __builtin_amdgcn_global_load_lds(
        (const __attribute__((address_space(1))) unsigned int*)(uintptr_t)g,
        (__attribute__((address_space(3))) unsigned int*)(uintptr_t)l,
        16, 0, 0);
}

__device__ __forceinline__ short f2bf(float f) {
    __hip_bfloat16 h = __float2bfloat16(f);
    return *reinterpret_cast<short*>(&h);
}

// ---------------------------------------------------------------------------
// prep1: fused X cast + Wqkv transpose-cast (phi-permuted) + Wo transpose-cast
// phi swaps bits 5<->6 of the within-head (128) column for Q/K heads so RoPE
// pairs (i, i+64) land in the same lane of the QKV gemm epilogue. Involution.
__global__ void prep1(const float* __restrict__ X, bf16* __restrict__ Xb,
                      const float* __restrict__ Wqkv, bf16* __restrict__ Wqkvt,
                      const float* __restrict__ Wo, bf16* __restrict__ Wot)
{
    __shared__ float t[32][33];
    int bid = blockIdx.x;
    if (bid < 8192) {
        long idx = ((long)bid * 256 + threadIdx.x) * 4;
        float4 v = *(const float4*)(X + idx);
        bf16 o[4];
        o[0] = __float2bfloat16(v.x); o[1] = __float2bfloat16(v.y);
        o[2] = __float2bfloat16(v.z); o[3] = __float2bfloat16(v.w);
        *(ulong1*)(Xb + idx) = *(ulong1*)o;
        return;
    }
    const float* in; bf16* out; int R, C, bx, by; bool perm;
    if (bid < 13312) {
        int v = bid - 8192;          // (80, 64)
        bx = v % 80; by = v / 80;
        in = Wqkv; out = Wqkvt; R = HID_; C = QKV_N; perm = true;
    } else {
        int v = bid - 13312;         // (64, 64)
        bx = v & 63; by = v >> 6;
        in = Wo; out = Wot; R = HID_; C = HID_; perm = false;
    }
    int tx = threadIdx.x & 31, ty = threadIdx.x >> 5;   // 32x8
    int c = bx * 32 + tx;
#pragma unroll
    for (int j = 0; j < 4; j++) {
        int r = by * 32 + ty + j * 8;
        t[ty + j * 8][tx] = in[(long)r * C + c];
    }
    __syncthreads();
#pragma unroll
    for (int j = 0; j < 4; j++) {
        int cc = bx * 32 + ty + j * 8;
        int rr = by * 32 + tx;
        int ccp = cc;
        if (perm && cc < (NH_ + NKV_) * HD_)   // Q/K heads: swap bits 5,6
            ccp = (cc & ~0x60) | ((cc & 0x20) << 1) | ((cc & 0x40) >> 1);
        out[(long)ccp * R + rr] = __float2bfloat16(t[tx][ty + j * 8]);
    }
}

// ---------------------------------------------------------------------------
// v_transpose: Vtmp[b][s][j] (bias already applied) -> VtG[b][j][sigma(s)],
// sigma = swap bits 2<->3 of s (PV A-fragment key ordering).
__global__ void v_transpose(const bf16* __restrict__ Vtmp, bf16* __restrict__ VtG) {
    __shared__ bf16 t[32][33];
    int v = blockIdx.x;                       // (8, 64, 2) flattened
    int j0 = (v & 7) * 32;
    int s0 = ((v >> 3) & 63) * 32;
    int b = v >> 9;
    int tx = threadIdx.x & 31, ty = threadIdx.x >> 5;   // 32x8
#pragma unroll
    for (int jj = 0; jj < 4; jj++) {
        int s = s0 + ty + jj * 8;
        t[ty + jj * 8][tx] = Vtmp[((long)b * S_ + s) * 256 + j0 + tx];
    }
    __syncthreads();
    int txp = (tx & 0x13) | ((tx & 4) << 1) | ((tx & 8) >> 1);  // swap bits 2,3
#pragma unroll
    for (int jj = 0; jj < 4; jj++) {
        int j = j0 + ty + jj * 8;
        VtG[((long)b * (2 * HD_) + j) * S_ + s0 + txp] = t[tx][ty + jj * 8];
    }
}

// ---------------------------------------------------------------------------
// QKV GEMM with fused bias + RoPE epilogue. 128x128 tile, BK=64.
// XCD-chunked swizzle (T1): grid 20x32 = 640 = 8*80 blocks.
__global__ __launch_bounds__(256, 3) void gemm_qkv(
    const bf16* __restrict__ A, const bf16* __restrict__ Bt,
    const float* __restrict__ bias, const int* __restrict__ pos,
    bf16* __restrict__ Qr, bf16* __restrict__ Kr, bf16* __restrict__ Vtmp)
{
    __shared__ __align__(16) bf16 As[128 * 64];
    __shared__ __align__(16) bf16 Bs[128 * 64];
    const int K = HID_;
    const int tid = threadIdx.x;
    const int wave = tid >> 6, lane = tid & 63;
    const int quad = lane >> 4, l16 = lane & 15;
    const int wr = wave >> 1, wc = wave & 1;

    // T1 XCD swizzle: bijective since nwg % 8 == 0
    const int nwg  = gridDim.x * gridDim.y;
    const int orig = blockIdx.y * gridDim.x + blockIdx.x;
    const int swz  = (orig & 7) * (nwg >> 3) + (orig >> 3);
    const int bx = swz % gridDim.x, by = swz / gridDim.x;

    const long row0 = (long)by * 128;
    const long col0 = (long)bx * 128;

    f32x4 acc[4][4];
#pragma unroll
    for (int i = 0; i < 4; i++)
#pragma unroll
        for (int j = 0; j < 4; j++) acc[i][j] = {0.f, 0.f, 0.f, 0.f};

    for (int k0 = 0; k0 < K; k0 += 64) {
        __syncthreads();
#pragma unroll
        for (int i = 0; i < 4; i++) {
            int cb = i * 256 + wave * 64;
            int c = cb + lane;
            int r = c >> 3, sc = c & 7;
            int gc = sc ^ (r & 7);
            async_load16(A + (row0 + r) * K + k0 + gc * 8, As + (size_t)cb * 8);
            async_load16(Bt + (col0 + r) * K + k0 + gc * 8, Bs + (size_t)cb * 8);
        }
        __syncthreads();

#pragma unroll
        for (int ks2 = 0; ks2 < 2; ks2++) {
            const int slot = ((ks2 * 4 + quad) ^ (l16 & 7)) * 8;
            bf16x8 af[4], bfr[4];
#pragma unroll
            for (int mi = 0; mi < 4; mi++)
                af[mi] = *(const bf16x8*)(As + (wr * 64 + mi * 16 + l16) * 64 + slot);
#pragma unroll
            for (int ni = 0; ni < 4; ni++)
                bfr[ni] = *(const bf16x8*)(Bs + (wc * 64 + ni * 16 + l16) * 64 + slot);
#pragma unroll
            for (int mi = 0; mi < 4; mi++)
#pragma unroll
                for (int ni = 0; ni < 4; ni++)
                    acc[mi][ni] = __builtin_amdgcn_mfma_f32_16x16x32_bf16(
                        af[mi], bfr[ni], acc[mi][ni], 0, 0, 0);
        }
    }

    const int ct = bx;
    if (ct < NH_ + NKV_) {
        // RoPE heads (Q or K)
        const bool isQ = (ct < NH_);
        float invf[2];
#pragma unroll
        for (int np = 0; np < 2; np++) {
            int i = wc * 32 + np * 16 + l16;
            invf[np] = __expf(-(float)i * (13.815510557964274f / 64.0f));
        }
#pragma unroll
        for (int mi = 0; mi < 4; mi++) {
            long r0 = row0 + wr * 64 + mi * 16 + quad * 4;
#pragma unroll
            for (int reg = 0; reg < 4; reg++) {
                long rr = r0 + reg;
                int b = (int)(rr >> 11), s = (int)(rr & 2047);
                float p = (float)pos[rr];
#pragma unroll
                for (int np = 0; np < 2; np++) {
                    int i = wc * 32 + np * 16 + l16;
                    float x1 = acc[mi][np][reg]     + bias[ct * 128 + i];
                    float x2 = acc[mi][np + 2][reg] + bias[ct * 128 + i + 64];
                    float sn, cs;
                    __sincosf(p * invf[np], &sn, &cs);
                    float o1 = x1 * cs - x2 * sn;
                    float o2 = x2 * cs + x1 * sn;
                    if (isQ) {
                        long ob = (((long)b * NH_ + ct) * S_ + s) * HD_;
                        Qr[ob + i]      = __float2bfloat16(o1 * QSCALE_);
                        Qr[ob + i + 64] = __float2bfloat16(o2 * QSCALE_);
                    } else {
                        long ob = (((long)b * NKV_ + (ct - NH_)) * S_ + s) * HD_;
                        Kr[ob + i]      = __float2bfloat16(o1);
                        Kr[ob + i + 64] = __float2bfloat16(o2);
                    }
                }
            }
        }
    } else {
        // V heads: bias only, natural [b*S+s][256] layout
#pragma unroll
        for (int mi = 0; mi < 4; mi++) {
            long r0 = row0 + wr * 64 + mi * 16 + quad * 4;
#pragma unroll
            for (int ni = 0; ni < 4; ni++) {
                int c = wc * 64 + ni * 16 + l16;
                float bv = bias[ct * 128 + c];
#pragma unroll
                for (int reg = 0; reg < 4; reg++)
                    Vtmp[(r0 + reg) * 256 + (ct - 18) * 128 + c] =
                        __float2bfloat16(acc[mi][ni][reg] + bv);
            }
        }
    }
}

// ---------------------------------------------------------------------------
// Output projection GEMM: 128x128 tile, BK=64, fp32 out. T1 swizzle (512=8*64).
__global__ __launch_bounds__(256, 3) void gemm_out(
    const bf16* __restrict__ A, const bf16* __restrict__ Bt,
    float* __restrict__ Cout, int M, int N, int K)
{
    __shared__ __align__(16) bf16 As[128 * 64];
    __shared__ __align__(16) bf16 Bs[128 * 64];
    const int tid = threadIdx.x;
    const int wave = tid >> 6, lane = tid & 63;
    const int quad = lane >> 4, l16 = lane & 15;
    const int wr = wave >> 1, wc = wave & 1;

    // T1 XCD swizzle: bijective since nwg % 8 == 0
    const int nwg  = gridDim.x * gridDim.y;
    const int orig = blockIdx.y * gridDim.x + blockIdx.x;
    const int swz  = (orig & 7) * (nwg >> 3) + (orig >> 3);
    const int bx = swz % gridDim.x, by = swz / gridDim.x;

    const long row0 = (long)by * 128;
    const long col0 = (long)bx * 128;

    f32x4 acc[4][4];
#pragma unroll
    for (int i = 0; i < 4; i++)
#pragma unroll
        for (int j = 0; j < 4; j++) acc[i][j] = {0.f, 0.f, 0.f, 0.f};

    for (int k0 = 0; k0 < K; k0 += 64) {
        __syncthreads();
#pragma unroll
        for (int i = 0; i < 4; i++) {
            int cb = i * 256 + wave * 64;
            int c = cb + lane;
            int r = c >> 3, sc = c & 7;
            int gc = sc ^ (r & 7);
            async_load16(A + (row0 + r) * K + k0 + gc * 8, As + (size_t)cb * 8);
            async_load16(Bt + (col0 + r) * K + k0 + gc * 8, Bs + (size_t)cb * 8);
        }
        __syncthreads();

#pragma unroll
        for (int ks2 = 0; ks2 < 2; ks2++) {
            const int slot = ((ks2 * 4 + quad) ^ (l16 & 7)) * 8;
            bf16x8 af[4], bfr[4];
#pragma unroll
            for (int mi = 0; mi < 4; mi++)
                af[mi] = *(const bf16x8*)(As + (wr * 64 + mi * 16 + l16) * 64 + slot);
#pragma unroll
            for (int ni = 0; ni < 4; ni++)
                bfr[ni] = *(const bf16x8*)(Bs + (wc * 64 + ni * 16 + l16) * 64 + slot);
#pragma unroll
            for (int mi = 0; mi < 4; mi++)
#pragma unroll
                for (int ni = 0; ni < 4; ni++)
                    acc[mi][ni] = __builtin_amdgcn_mfma_f32_16x16x32_bf16(
                        af[mi], bfr[ni], acc[mi][ni], 0, 0, 0);
        }
    }

#pragma unroll
    for (int mi = 0; mi < 4; mi++) {
        long r = row0 + wr * 64 + mi * 16 + quad * 4;
#pragma unroll
        for (int ni = 0; ni < 4; ni++) {
            long c = col0 + wc * 64 + ni * 16 + l16;
#pragma unroll
            for (int reg = 0; reg < 4; reg++)
                Cout[(r + reg) * N + c] = acc[mi][ni][reg];
        }
    }
}

// ---------------------------------------------------------------------------
// Causal GQA flash attention, 32x32x16 MFMA, 128q x 64k tiles, 4 waves.
// Round-5 restructure: the two 32-key subtiles of each kt are fused into ONE
// straight-line block (common case): QK0;QK1;SM0;SM1;PV0;PV1 -> two
// independent 8-MFMA QK chains (ILP=2), softmax VALU slides under MFMA.
// Subtile0 in the fused path is provably unmasked (mask code deleted);
// the single-subtile path is provably triangular. lsum split into two
// independent accumulators. No setprio (measured regression, lockstep waves).
__global__ __launch_bounds__(256, 2) void attn_kernel(
    const bf16* __restrict__ Q,   // [B][NH][S][HD], pre-scaled by SCALE*log2e
    const bf16* __restrict__ Kk,  // [B][NKV][S][HD]
    const bf16* __restrict__ Vt,  // [B][NKV*HD][sigma(S)]
    bf16* __restrict__ O)         // [B][S][NH*HD]
{
    const int id = blockIdx.x;
    const int hb = id & 31;
    const int h = hb & 15, b = hb >> 4;
    const int q4 = (id >> 5) & 7, hi = id >> 8;
    const int qtile = hi ? (15 - q4) : q4;    // co-resident pair sums to 15
    const int kvh = h >> 3;
    const int tid = threadIdx.x, wave = tid >> 6, lane = tid & 63;
    const int l31 = lane & 31, half = lane >> 5;
    const int qh = wave;                      // q rows qh*32..+31

    __shared__ __align__(16) char smem[64 * 1024];
    __shared__ float Ls[128];

    const bf16* Kbase = Kk + ((long)(b * NKV_ + kvh) * S_) * HD_;
    const bf16* Vbase = Vt + ((long)b * (2 * HD_) + kvh * HD_) * (long)S_;

    // stage all 128 Q rows (32 KB across both halves of buf0), hoist B-frags
    const bf16* Qg = Q + (((long)(b * NH_ + h) * S_) + qtile * 128) * HD_;
    bf16* Qs = (bf16*)smem;
#pragma unroll
    for (int i = 0; i < 8; i++) {
        int cb = i * 256 + wave * 64;
        int c = cb + lane, r = c >> 4, sc = c & 15;
        async_load16(Qg + r * HD_ + (sc ^ (r & 15)) * 8, Qs + (size_t)cb * 8);
    }
    __syncthreads();
    bf16x8 qf[8];
#pragma unroll
    for (int ks = 0; ks < 8; ks++) {
        int gc = 2 * ks + half;
        qf[ks] = *(const bf16x8*)(Qs + (qh * 32 + l31) * 128 +
                                  ((gc ^ (l31 & 15)) * 8));
    }
    __syncthreads();   // smem now reusable for K/V tiles

    f32x16 acc_o[4];
#pragma unroll
    for (int r = 0; r < 16; r++) {
        acc_o[0][r] = 0.f; acc_o[1][r] = 0.f;
        acc_o[2][r] = 0.f; acc_o[3][r] = 0.f;
    }
    float lsum0 = 0.f, lsum1 = 0.f;

    const int qc32 = qtile * 4 + qh;          // this wave's 32-q chunk index
    const int kt_max = 2 * qtile + 1;

    // prologue: issue kt=0 into buf 0
    {
        bf16* KsW  = (bf16*)smem;
        bf16* VtsW = (bf16*)(smem + 16384);
#pragma unroll
        for (int i = 0; i < 4; i++) {
            int cb = i * 256 + wave * 64;
            int c = cb + lane, r = c >> 4, sc = c & 15;
            async_load16(Kbase + r * HD_ + (sc ^ (r & 15)) * 8,
                         KsW + (size_t)cb * 8);
        }
#pragma unroll
        for (int i = 0; i < 4; i++) {
            int cb = i * 256 + wave * 64;
            int c = cb + lane, r = c >> 3, sc = c & 7;
            async_load16(Vbase + (long)r * S_ + (sc ^ (r & 7)) * 8,
                         VtsW + (size_t)cb * 8);
        }
    }

#pragma unroll 1
    for (int kt = 0; kt <= kt_max; kt++) {
        __syncthreads();   // buf[kt&1] complete; prev compute done everywhere
        const bf16* Ks  = (const bf16*)(smem + (kt & 1) * 32768);
        const bf16* Vts = (const bf16*)(smem + (kt & 1) * 32768 + 16384);

        if (kt < kt_max) {   // prefetch kt+1 into the other buffer
            bf16* KsW  = (bf16*)(smem + ((kt + 1) & 1) * 32768);
            bf16* VtsW = (bf16*)(smem + ((kt + 1) & 1) * 32768 + 16384);
            const bf16* Kg = Kbase + (long)(kt + 1) * 64 * HD_;
#pragma unroll
            for (int i = 0; i < 4; i++) {
                int cb = i * 256 + wave * 64;
                int c = cb + lane, r = c >> 4, sc = c & 15;
                async_load16(Kg + r * HD_ + (sc ^ (r & 15)) * 8,
                             KsW + (size_t)cb * 8);
            }
            const bf16* Vg = Vbase + (kt + 1) * 64;
#pragma unroll
            for (int i = 0; i < 4; i++) {
                int cb = i * 256 + wave * 64;
                int c = cb + lane, r = c >> 3, sc = c & 7;
                async_load16(Vg + (long)r * S_ + (sc ^ (r & 7)) * 8,
                             VtsW + (size_t)cb * 8);
            }
        }

        // --- fused dual-subtile compute -----------------------------------
        auto qk = [&](int mh, f32x16& st) {
#pragma unroll
            for (int ks = 0; ks < 8; ks++) {
                int gc = 2 * ks + half;
                bf16x8 ka = *(const bf16x8*)(Ks + (mh * 32 + l31) * 128 +
                                             ((gc ^ (l31 & 15)) * 8));
                st = __builtin_amdgcn_mfma_f32_32x32x16_bf16(ka, qf[ks], st,
                                                             0, 0, 0);
            }
        };
        auto smax = [&](const f32x16& st, bool tri, bf16x8 (&pa)[2],
                        float& ls) {
#pragma unroll
            for (int t = 0; t < 2; t++)
#pragma unroll
                for (int j = 0; j < 8; j++) {
                    int r = t * 8 + j;
                    int krow = (r & 3) + 8 * (r >> 2) + 4 * half;
                    float x = st[r];
                    if (tri && krow > l31) x = -1e30f;
                    float pv = __builtin_amdgcn_exp2f(x);
                    ls += pv;                 // lane l31 = q here
                    pa[t][j] = f2bf(pv);
                }
        };
        auto pv_acc = [&](int mh, bf16x8 (&pa)[2]) {
#pragma unroll
            for (int t = 0; t < 2; t++) {
                int gc = 4 * mh + 2 * t + half;
#pragma unroll
                for (int nt = 0; nt < 4; nt++) {
                    bf16x8 vb = *(const bf16x8*)(Vts + (nt * 32 + l31) * 64 +
                                                 ((gc ^ (l31 & 7)) * 8));
                    acc_o[nt] = __builtin_amdgcn_mfma_f32_32x32x16_bf16(
                        pa[t], vb, acc_o[nt], 0, 0, 0);
                }
            }
        };

        const int kc0 = 2 * kt, kc1 = 2 * kt + 1;
        if (kc1 <= qc32) {
            // both subtiles live; subtile0 provably unmasked (kc0 < qc32)
            f32x16 st0, st1;
#pragma unroll
            for (int r = 0; r < 16; r++) { st0[r] = 0.f; st1[r] = 0.f; }
            qk(0, st0);
            qk(1, st1);
            bf16x8 pa0[2], pa1[2];
            smax(st0, false, pa0, lsum0);
            smax(st1, kc1 == qc32, pa1, lsum1);
            pv_acc(0, pa0);
            pv_acc(1, pa1);
        } else if (kc0 <= qc32) {
            // single subtile; provably triangular (kc0 == qc32)
            f32x16 st0;
#pragma unroll
            for (int r = 0; r < 16; r++) st0[r] = 0.f;
            qk(0, st0);
            bf16x8 pa0[2];
            smax(st0, true, pa0, lsum0);
            pv_acc(0, pa0);
        }
    }

    // row-sum broadcast: lsum indexed by lane=q; acc_o rows are reg-indexed q.
    float lsum = lsum0 + lsum1;
    float ltot = lsum + __shfl_xor(lsum, 32);
    __syncthreads();   // all compute done before Ls write
    if (half == 0) Ls[qh * 32 + l31] = ltot;
    __syncthreads();

    float inv_l[16];
#pragma unroll
    for (int r = 0; r < 16; r++) {
        int qrow = (r & 3) + 8 * (r >> 2) + 4 * half;
        inv_l[r] = __builtin_amdgcn_rcpf(Ls[qh * 32 + qrow]);
    }
#pragma unroll
    for (int nt = 0; nt < 4; nt++)
#pragma unroll
        for (int r = 0; r < 16; r++) {
            int qrow = (r & 3) + 8 * (r >> 2) + 4 * half;
            float v = acc_o[nt][r] * inv_l[r];
            O[((long)b * S_ + qtile * 128 + qh * 32 + qrow) * (NH_ * HD_) +
              h * HD_ + nt * 32 + l31] = __float2bfloat16(v);
        }
}

// ---------------------------------------------------------------------------
extern "C" void kernel_launch(void* const* d_in, const int* in_sizes, int n_in,
                              void* d_out, int out_size, void* d_ws, size_t ws_size,
                              hipStream_t stream) {
    const int*   pos  = (const int*)d_in[0];
    const float* X    = (const float*)d_in[1];
    const float* Wqkv = (const float*)d_in[2];
    const float* bqkv = (const float*)d_in[3];
    const float* Wo   = (const float*)d_in[4];
    float* out = (float*)d_out;

    char* ws = (char*)d_ws;
    bf16* Xb    = (bf16*)ws;  ws += (size_t)B_ * S_ * HID_ * 2;
    bf16* Wqkvt = (bf16*)ws;  ws += (size_t)QKV_N * HID_ * 2;
    bf16* Wot   = (bf16*)ws;  ws += (size_t)HID_ * HID_ * 2;
    bf16* Qr    = (bf16*)ws;  ws += (size_t)B_ * NH_ * S_ * HD_ * 2;
    bf16* Kr    = (bf16*)ws;  ws += (size_t)B_ * NKV_ * S_ * HD_ * 2;
    bf16* Vtmp  = (bf16*)ws;  ws += (size_t)B_ * S_ * 2 * HD_ * 2;
    bf16* VtG   = (bf16*)ws;  ws += (size_t)B_ * NKV_ * HD_ * S_ * 2;
    bf16* AO    = (bf16*)ws;  ws += (size_t)B_ * S_ * NH_ * HD_ * 2;

    // 1. fused cast + weight transposes (Wqkvt phi-permuted)
    prep1<<<17408, 256, 0, stream>>>(X, Xb, Wqkv, Wqkvt, Wo, Wot);

    // 2. QKV projection + bias + RoPE fused epilogue (640 blocks, T1 swizzle)
    gemm_qkv<<<dim3(QKV_N / 128, (B_ * S_) / 128), 256, 0, stream>>>(
        Xb, Wqkvt, bqkv, pos, Qr, Kr, Vtmp);

    // 3. V transpose (sigma key permutation)
    v_transpose<<<1024, 256, 0, stream>>>(Vtmp, VtG);

    // 4. causal GQA attention (512 blocks, 128q tiles, balanced qtile swizzle)
    attn_kernel<<<dim3(512), 256, 0, stream>>>(Qr, Kr, VtG, AO);

    // 5. output projection (512 blocks, T1 swizzle, fp32 out)
    gemm_out<<<dim3(HID_ / 128, (B_ * S_) / 128), 256, 0, stream>>>(
        AO, Wot, out, B_ * S_, HID_, HID_);
}